// Round 10
// baseline (454.561 us; speedup 1.0000x reference)
//
#include <hip/hip_runtime.h>

constexpr int NSTAY = 100000;
constexpr int NDIAG = 50000;
constexpr int NE    = 1000000;
constexpr int CAP   = 64;       // bucket capacity; deg ~Binom(1e6, 1e-5..2e-5), P(deg>64) ~ 0
constexpr int PCAP  = 160000;   // per-chunk partition capacity (mean 125000, sigma ~331)
constexpr int BCAP  = 280;      // LDS bin capacity (mean 128, sigma ~10.6)

typedef __attribute__((ext_vector_type(8))) short bf16x8;
typedef __attribute__((ext_vector_type(4))) float f32x4;
typedef __attribute__((ext_vector_type(4))) float fvec4;
typedef __attribute__((ext_vector_type(4))) int   i32x4;

__device__ __forceinline__ float b2f(unsigned short u) {
  union { unsigned int i; float f; } v; v.i = (unsigned int)u << 16; return v.f;
}
__device__ __forceinline__ unsigned short f2b(float f) {
  union { float f; unsigned int i; } v; v.f = f;
  unsigned int r = (v.i + 0x7fffu + ((v.i >> 16) & 1u)) >> 16;   // RNE
  return (unsigned short)r;
}
__device__ __forceinline__ bf16x8 ldb8(const unsigned short* p) {
  return *reinterpret_cast<const bf16x8*>(p);
}
__device__ __forceinline__ f32x4 mfma16(bf16x8 a, bf16x8 b, f32x4 c) {
  return __builtin_amdgcn_mfma_f32_16x16x32_bf16(a, b, c, 0, 0, 0);
}

// ---------------- fused weight prep + cnt/gcur zeroing ----------------
__global__ __launch_bounds__(256) void k_prep(const float* __restrict__ Wps,
    const float* __restrict__ Wpd, const float* __restrict__ Wl,
    const float* __restrict__ Wr, unsigned short* __restrict__ Wps_b,
    unsigned short* __restrict__ Wpd_b, unsigned short* __restrict__ Wc6,
    int* __restrict__ cnt, int* __restrict__ gcur) {
  int i = blockIdx.x * 256 + threadIdx.x;
  if (i < 8192) {
    Wps_b[i] = f2b(Wps[i]);
  } else if (i < 12288) {
    Wpd_b[i - 8192] = f2b(Wpd[i - 8192]);
  } else if (i < 61440) {
    int t = i - 12288;
    int k = t & 127, f = (t >> 7) & 63, ty = t >> 13;
    float v = (k < 64) ? Wl[ty * 4096 + f * 64 + k] : Wr[ty * 4096 + f * 64 + (k - 64)];
    Wc6[t] = f2b(v);
  } else if (i < 61440 + 250000) {
    cnt[i - 61440] = 0;
  } else if (i < 61440 + 250000 + 24) {
    gcur[i - 61440 - 250000] = 0;
  }
}

// ---------------- MFMA input projection: out = relu(x @ Wb.T + b), K = NKC*32, x f32 (nt) ----------------
template<int NKC>
__global__ __launch_bounds__(256) void k_projM(const float* __restrict__ x,
    const unsigned short* __restrict__ Wb, const float* __restrict__ bias,
    unsigned short* __restrict__ out, int n) {
  const int lane = threadIdx.x & 63;
  const int wv   = threadIdx.x >> 6;
  const int r    = lane & 15;
  const int kg   = lane >> 4;
  const int tile0 = (blockIdx.x * 4 + wv) * 16;
  if (tile0 >= n) return;
  const int K = NKC * 32;
  bf16x8 Bf[4][NKC];
  #pragma unroll
  for (int nt = 0; nt < 4; ++nt)
    #pragma unroll
    for (int kc = 0; kc < NKC; ++kc)
      Bf[nt][kc] = ldb8(Wb + (nt * 16 + r) * K + kc * 32 + kg * 8);
  const int node = tile0 + r;
  const bool ok = node < n;
  bf16x8 Af[NKC] = {};
  if (ok) {
    #pragma unroll
    for (int kc = 0; kc < NKC; ++kc) {
      const float* px = x + (size_t)node * K + kc * 32 + kg * 8;
      fvec4 lo = __builtin_nontemporal_load(reinterpret_cast<const fvec4*>(px));
      fvec4 hi = __builtin_nontemporal_load(reinterpret_cast<const fvec4*>(px + 4));
      bf16x8 a;
      a[0] = (short)f2b(lo.x); a[1] = (short)f2b(lo.y);
      a[2] = (short)f2b(lo.z); a[3] = (short)f2b(lo.w);
      a[4] = (short)f2b(hi.x); a[5] = (short)f2b(hi.y);
      a[6] = (short)f2b(hi.z); a[7] = (short)f2b(hi.w);
      Af[kc] = a;
    }
  }
  f32x4 acc[4];
  #pragma unroll
  for (int nt = 0; nt < 4; ++nt) {
    f32x4 c = {0.f, 0.f, 0.f, 0.f};
    #pragma unroll
    for (int kc = 0; kc < NKC; ++kc)
      c = mfma16(Af[kc], Bf[nt][kc], c);
    acc[nt] = c;
  }
  #pragma unroll
  for (int j = 0; j < 4; ++j) {
    int m = tile0 + kg * 4 + j;
    if (m < n) {
      size_t base = (size_t)m * 64 + r;
      #pragma unroll
      for (int nt = 0; nt < 4; ++nt)
        out[base + nt * 16] = f2b(fmaxf(acc[nt][j] + bias[nt * 16 + r], 0.f));
    }
  }
}

// ---------------- phase 1: partition edges by dst-octant (LDS-binned, coalesced flush) ----------------
// grid 3*1024; ty = blockIdx>>10. Output: part[ty][chunk] packed u32 = (dloc<<17)|src.
__global__ __launch_bounds__(256) void k_part(
    const int* __restrict__ s0, const int* __restrict__ d0, int cpc0,
    const int* __restrict__ s1, const int* __restrict__ d1, int cpc1,
    const int* __restrict__ s2, const int* __restrict__ d2, int cpc2,
    unsigned int* __restrict__ part, int* __restrict__ gcur) {
  __shared__ unsigned int buf[8][BCAP];
  __shared__ int bcnt[8];
  __shared__ int bbase[8];
  const int ty = blockIdx.x >> 10;
  const int bx = blockIdx.x & 1023;
  const int* src; const int* dst; int cpc;
  if (ty == 0)      { src = s0; dst = d0; cpc = cpc0; }
  else if (ty == 1) { src = s1; dst = d1; cpc = cpc1; }
  else              { src = s2; dst = d2; cpc = cpc2; }
  if (threadIdx.x < 8) bcnt[threadIdx.x] = 0;
  __syncthreads();
  const int NE4 = NE / 4;
  int i = bx * 256 + threadIdx.x;
  if (i < NE4) {
    i32x4 dd = __builtin_nontemporal_load(reinterpret_cast<const i32x4*>(dst) + i);
    i32x4 ss = __builtin_nontemporal_load(reinterpret_cast<const i32x4*>(src) + i);
    #pragma unroll
    for (int u = 0; u < 4; ++u) {
      int d = dd[u];
      int b = d / cpc;                       // < 8 since 8*cpc >= n
      unsigned int pk = ((unsigned int)(d - b * cpc) << 17) | (unsigned int)ss[u];
      int p = atomicAdd(&bcnt[b], 1);
      if (p < BCAP) buf[b][p] = pk;
    }
  }
  __syncthreads();
  if (threadIdx.x < 8) {
    int c = bcnt[threadIdx.x]; if (c > BCAP) c = BCAP;
    bcnt[threadIdx.x] = c;
    bbase[threadIdx.x] = atomicAdd(&gcur[ty * 8 + threadIdx.x], c);
  }
  __syncthreads();
  #pragma unroll
  for (int b = 0; b < 8; ++b) {
    int c = bcnt[b], base = bbase[b];
    unsigned int* op = part + ((size_t)ty * 8 + b) * PCAP + base;
    for (int t = threadIdx.x; t < c; t += 256)
      op[t] = buf[b][t];
  }
}

// ---------------- phase 2: XCD-local bucket scatter (chunk c -> blocks with blockIdx&7==c) ----------------
// grid 2048 (all co-resident); types sequential inside so per-XCD bucket set fits L2.
__global__ __launch_bounds__(256) void k_bscatter(
    const unsigned int* __restrict__ part, const int* __restrict__ gcur,
    int* c0, int* __restrict__ b0, int cpc0,
    int* c1, int* __restrict__ b1, int cpc1,
    int* c2, int* __restrict__ b2, int cpc2) {
  const int ch  = blockIdx.x & 7;
  const int sub = (blockIdx.x >> 3) * 256 + threadIdx.x;   // 0..65535
  #pragma unroll
  for (int ty = 0; ty < 3; ++ty) {
    int* cnt; int* bkt; int cpc;
    if (ty == 0)      { cnt = c0; bkt = b0; cpc = cpc0; }
    else if (ty == 1) { cnt = c1; bkt = b1; cpc = cpc1; }
    else              { cnt = c2; bkt = b2; cpc = cpc2; }
    const unsigned int* p = part + ((size_t)ty * 8 + ch) * PCAP;
    const int n = gcur[ty * 8 + ch];
    for (int t = sub; t < n; t += 65536) {
      unsigned int v = p[t];
      int d = ch * cpc + (int)(v >> 17);
      int s = (int)(v & 0x1FFFFu);
      int pos = atomicAdd(&cnt[d], 1);
      if (pos < CAP) bkt[(size_t)d * CAP + pos] = s;
    }
  }
}

// ---------------- merged gather-mean ----------------
// node space: [0,NSTAY) s2s from hs | [NSTAY,2*NSTAY) d2s from hd | [2*NSTAY,+NDIAG) s2d from hs
__global__ __launch_bounds__(256) void k_gather3(
    const unsigned short* __restrict__ hs, const unsigned short* __restrict__ hd,
    const int* __restrict__ cnt2, const int* __restrict__ bkt2, unsigned short* __restrict__ agg2,
    const int* __restrict__ cnt1, const int* __restrict__ bkt1, unsigned short* __restrict__ agg1,
    const int* __restrict__ cntD, const int* __restrict__ bktD, unsigned short* __restrict__ aggD,
    int ntot) {
  const int lane = threadIdx.x & 63;
  const int grp  = lane >> 4;          // 0..3
  const int fl   = lane & 15;          // feature quad
  int gw = (blockIdx.x * 256 + threadIdx.x) >> 6;
  const int nw = (gridDim.x * 256) >> 6;
  for (int gn = gw; gn < ntot; gn += nw) {
    const unsigned short* h; const int* cnt; const int* bkt; unsigned short* agg; int node;
    if (gn < NSTAY)            { h = hs; cnt = cnt2; bkt = bkt2; agg = agg2; node = gn; }
    else if (gn < 2 * NSTAY)   { h = hd; cnt = cnt1; bkt = bkt1; agg = agg1; node = gn - NSTAY; }
    else                       { h = hs; cnt = cntD; bkt = bktD; agg = aggD; node = gn - 2 * NSTAY; }
    const int e  = cnt[node];
    const int em = (e < CAP) ? e : CAP;
    const int* row = bkt + (size_t)node * CAP;
    float ax = 0, ay = 0, az = 0, aw = 0;
    float bx = 0, by = 0, bz = 0, bw = 0;
    int j = 0;
    for (; j + 8 <= em; j += 8) {
      int i0 = row[j + grp];
      int i1 = row[j + grp + 4];
      ushort4 v0 = *(const ushort4*)(h + (size_t)i0 * 64 + fl * 4);
      ushort4 v1 = *(const ushort4*)(h + (size_t)i1 * 64 + fl * 4);
      ax += b2f(v0.x); ay += b2f(v0.y); az += b2f(v0.z); aw += b2f(v0.w);
      bx += b2f(v1.x); by += b2f(v1.y); bz += b2f(v1.z); bw += b2f(v1.w);
    }
    if (j + grp < em) {
      int i0 = row[j + grp];
      ushort4 v0 = *(const ushort4*)(h + (size_t)i0 * 64 + fl * 4);
      ax += b2f(v0.x); ay += b2f(v0.y); az += b2f(v0.z); aw += b2f(v0.w);
    }
    if (j + grp + 4 < em) {
      int i1 = row[j + grp + 4];
      ushort4 v1 = *(const ushort4*)(h + (size_t)i1 * 64 + fl * 4);
      bx += b2f(v1.x); by += b2f(v1.y); bz += b2f(v1.z); bw += b2f(v1.w);
    }
    ax += bx; ay += by; az += bz; aw += bw;
    ax += __shfl_xor(ax, 16); ay += __shfl_xor(ay, 16);
    az += __shfl_xor(az, 16); aw += __shfl_xor(aw, 16);
    ax += __shfl_xor(ax, 32); ay += __shfl_xor(ay, 32);
    az += __shfl_xor(az, 32); aw += __shfl_xor(aw, 32);
    if (grp == 0) {
      float inv = (e > 0) ? 1.0f / (float)e : 1.0f;
      ushort4 o = make_ushort4(f2b(ax * inv), f2b(ay * inv), f2b(az * inv), f2b(aw * inv));
      *(ushort4*)(agg + (size_t)node * 64 + fl * 4) = o;
    }
  }
}

// ---------------- fused stay-side SAGE: two edge types + hetero-mean + relu + LN (+cls) ----------------
template<int CLS>
__global__ __launch_bounds__(256) void k_sage2(
    const unsigned short* __restrict__ agg2b,
    const unsigned short* __restrict__ agg1b,
    unsigned short* hb,
    const unsigned short* __restrict__ W2b, const float* __restrict__ bl2,
    const unsigned short* __restrict__ W1b, const float* __restrict__ bl1,
    const float* __restrict__ g, const float* __restrict__ bln, int n,
    const float* __restrict__ Wcf, const float* __restrict__ bcf,
    float* __restrict__ outp) {
  const int lane = threadIdx.x & 63;
  const int wv   = threadIdx.x >> 6;
  const int r    = lane & 15;
  const int kg   = lane >> 4;
  const int tile0 = (blockIdx.x * 4 + wv) * 16;
  if (tile0 >= n) return;
  const int node = tile0 + r;
  const bool ok = node < n;
  const size_t rowa = (size_t)node * 64 + kg * 8;
  bf16x8 A20 = {}, A21 = {}, A10 = {}, A11 = {}, H0 = {}, H1 = {};
  if (ok) {
    A20 = ldb8(agg2b + rowa); A21 = ldb8(agg2b + rowa + 32);
    A10 = ldb8(agg1b + rowa); A11 = ldb8(agg1b + rowa + 32);
    H0  = ldb8(hb + rowa);    H1  = ldb8(hb + rowa + 32);
  }
  f32x4 acc2[4], acc1[4];
  #pragma unroll
  for (int nt = 0; nt < 4; ++nt) {
    const unsigned short* wr = W2b + (nt * 16 + r) * 128 + kg * 8;
    f32x4 c = {0.f, 0.f, 0.f, 0.f};
    c = mfma16(A20, ldb8(wr), c);
    c = mfma16(A21, ldb8(wr + 32), c);
    c = mfma16(H0,  ldb8(wr + 64), c);
    c = mfma16(H1,  ldb8(wr + 96), c);
    acc2[nt] = c;
  }
  #pragma unroll
  for (int nt = 0; nt < 4; ++nt) {
    const unsigned short* wr = W1b + (nt * 16 + r) * 128 + kg * 8;
    f32x4 c = {0.f, 0.f, 0.f, 0.f};
    c = mfma16(A10, ldb8(wr), c);
    c = mfma16(A11, ldb8(wr + 32), c);
    c = mfma16(H0,  ldb8(wr + 64), c);
    c = mfma16(H1,  ldb8(wr + 96), c);
    acc1[nt] = c;
  }
  #pragma unroll
  for (int nt = 0; nt < 4; ++nt) {
    float b2 = bl2[nt * 16 + r], b1 = bl1[nt * 16 + r];
    #pragma unroll
    for (int j = 0; j < 4; ++j) { acc2[nt][j] += b2; acc1[nt][j] += b1; }
  }
  float ss2[4], ss1[4];
  #pragma unroll
  for (int j = 0; j < 4; ++j) {
    ss2[j] = acc2[0][j] * acc2[0][j] + acc2[1][j] * acc2[1][j]
           + acc2[2][j] * acc2[2][j] + acc2[3][j] * acc2[3][j];
    ss1[j] = acc1[0][j] * acc1[0][j] + acc1[1][j] * acc1[1][j]
           + acc1[2][j] * acc1[2][j] + acc1[3][j] * acc1[3][j];
  }
  #pragma unroll
  for (int off = 1; off < 16; off <<= 1) {
    #pragma unroll
    for (int j = 0; j < 4; ++j) {
      ss2[j] += __shfl_xor(ss2[j], off);
      ss1[j] += __shfl_xor(ss1[j], off);
    }
  }
  float v[4][4];
  #pragma unroll
  for (int j = 0; j < 4; ++j) {
    float ri2 = 1.0f / fmaxf(sqrtf(ss2[j]), 1e-12f);
    float ri1 = 1.0f / fmaxf(sqrtf(ss1[j]), 1e-12f);
    #pragma unroll
    for (int nt = 0; nt < 4; ++nt)
      v[nt][j] = fmaxf(0.5f * (acc2[nt][j] * ri2 + acc1[nt][j] * ri1), 0.f);
  }
  float s1[4], s2[4];
  #pragma unroll
  for (int j = 0; j < 4; ++j) {
    s1[j] = v[0][j] + v[1][j] + v[2][j] + v[3][j];
    s2[j] = v[0][j] * v[0][j] + v[1][j] * v[1][j] + v[2][j] * v[2][j] + v[3][j] * v[3][j];
  }
  #pragma unroll
  for (int off = 1; off < 16; off <<= 1) {
    #pragma unroll
    for (int j = 0; j < 4; ++j) {
      s1[j] += __shfl_xor(s1[j], off);
      s2[j] += __shfl_xor(s2[j], off);
    }
  }
  if (CLS == 0) {
    #pragma unroll
    for (int j = 0; j < 4; ++j) {
      int m = tile0 + kg * 4 + j;
      if (m >= n) continue;
      float mu  = s1[j] * (1.f / 64.f);
      float var = s2[j] * (1.f / 64.f) - mu * mu;
      float is  = 1.0f / sqrtf(var + 1e-5f);
      size_t base = (size_t)m * 64 + r;
      #pragma unroll
      for (int nt = 0; nt < 4; ++nt)
        hb[base + nt * 16] = f2b((v[nt][j] - mu) * is * g[nt * 16 + r] + bln[nt * 16 + r]);
    }
  } else {
    float wcc[3][4];
    #pragma unroll
    for (int c = 0; c < 3; ++c)
      #pragma unroll
      for (int nt = 0; nt < 4; ++nt) wcc[c][nt] = Wcf[c * 64 + nt * 16 + r];
    #pragma unroll
    for (int j = 0; j < 4; ++j) {
      int m = tile0 + kg * 4 + j;
      float mu  = s1[j] * (1.f / 64.f);
      float var = s2[j] * (1.f / 64.f) - mu * mu;
      float is  = 1.0f / sqrtf(var + 1e-5f);
      float p0 = 0.f, p1 = 0.f, p2 = 0.f;
      #pragma unroll
      for (int nt = 0; nt < 4; ++nt) {
        float hv = (v[nt][j] - mu) * is * g[nt * 16 + r] + bln[nt * 16 + r];
        p0 += hv * wcc[0][nt]; p1 += hv * wcc[1][nt]; p2 += hv * wcc[2][nt];
      }
      #pragma unroll
      for (int off = 1; off < 16; off <<= 1) {
        p0 += __shfl_xor(p0, off);
        p1 += __shfl_xor(p1, off);
        p2 += __shfl_xor(p2, off);
      }
      if (m < n && r < 3) {
        float pr = (r == 0) ? p0 : ((r == 1) ? p1 : p2);
        outp[(size_t)m * 3 + r] = pr + bcf[r];
      }
    }
  }
}

// ---------------- diag-side SAGE (single edge type) + relu + LN, in-place ----------------
__global__ __launch_bounds__(256) void k_sageD(
    const unsigned short* __restrict__ aggb,
    unsigned short* hb,
    const unsigned short* __restrict__ Wb, const float* __restrict__ bl,
    const float* __restrict__ g, const float* __restrict__ bln, int n) {
  const int lane = threadIdx.x & 63;
  const int wv   = threadIdx.x >> 6;
  const int r    = lane & 15;
  const int kg   = lane >> 4;
  const int tile0 = (blockIdx.x * 4 + wv) * 16;
  if (tile0 >= n) return;
  const int node = tile0 + r;
  const bool ok = node < n;
  const size_t rowa = (size_t)node * 64 + kg * 8;
  bf16x8 A0 = {}, A1 = {}, H0 = {}, H1 = {};
  if (ok) {
    A0 = ldb8(aggb + rowa); A1 = ldb8(aggb + rowa + 32);
    H0 = ldb8(hb + rowa);   H1 = ldb8(hb + rowa + 32);
  }
  f32x4 acc[4];
  #pragma unroll
  for (int nt = 0; nt < 4; ++nt) {
    const unsigned short* wr = Wb + (nt * 16 + r) * 128 + kg * 8;
    f32x4 c = {0.f, 0.f, 0.f, 0.f};
    c = mfma16(A0, ldb8(wr), c);
    c = mfma16(A1, ldb8(wr + 32), c);
    c = mfma16(H0, ldb8(wr + 64), c);
    c = mfma16(H1, ldb8(wr + 96), c);
    acc[nt] = c;
  }
  #pragma unroll
  for (int nt = 0; nt < 4; ++nt) {
    float bb = bl[nt * 16 + r];
    #pragma unroll
    for (int j = 0; j < 4; ++j) acc[nt][j] += bb;
  }
  float ss[4];
  #pragma unroll
  for (int j = 0; j < 4; ++j)
    ss[j] = acc[0][j] * acc[0][j] + acc[1][j] * acc[1][j]
          + acc[2][j] * acc[2][j] + acc[3][j] * acc[3][j];
  #pragma unroll
  for (int off = 1; off < 16; off <<= 1) {
    #pragma unroll
    for (int j = 0; j < 4; ++j) ss[j] += __shfl_xor(ss[j], off);
  }
  float v[4][4];
  #pragma unroll
  for (int j = 0; j < 4; ++j) {
    float ri = 1.0f / fmaxf(sqrtf(ss[j]), 1e-12f);
    #pragma unroll
    for (int nt = 0; nt < 4; ++nt) v[nt][j] = fmaxf(acc[nt][j] * ri, 0.f);
  }
  float s1[4], s2[4];
  #pragma unroll
  for (int j = 0; j < 4; ++j) {
    s1[j] = v[0][j] + v[1][j] + v[2][j] + v[3][j];
    s2[j] = v[0][j] * v[0][j] + v[1][j] * v[1][j] + v[2][j] * v[2][j] + v[3][j] * v[3][j];
  }
  #pragma unroll
  for (int off = 1; off < 16; off <<= 1) {
    #pragma unroll
    for (int j = 0; j < 4; ++j) {
      s1[j] += __shfl_xor(s1[j], off);
      s2[j] += __shfl_xor(s2[j], off);
    }
  }
  #pragma unroll
  for (int j = 0; j < 4; ++j) {
    int m = tile0 + kg * 4 + j;
    if (m >= n) continue;
    float mu  = s1[j] * (1.f / 64.f);
    float var = s2[j] * (1.f / 64.f) - mu * mu;
    float is  = 1.0f / sqrtf(var + 1e-5f);
    size_t base = (size_t)m * 64 + r;
    #pragma unroll
    for (int nt = 0; nt < 4; ++nt)
      hb[base + nt * 16] = f2b((v[nt][j] - mu) * is * g[nt * 16 + r] + bln[nt * 16 + r]);
  }
}

extern "C" void kernel_launch(void* const* d_in, const int* in_sizes, int n_in,
                              void* d_out, int out_size, void* d_ws, size_t ws_size,
                              hipStream_t stream) {
  const float* x_stay  = (const float*)d_in[0];
  const float* x_diag  = (const float*)d_in[1];
  const int*   s2d_src = (const int*)d_in[2];
  const int*   s2d_dst = (const int*)d_in[3];
  const int*   d2s_src = (const int*)d_in[4];
  const int*   d2s_dst = (const int*)d_in[5];
  const int*   s2s_src = (const int*)d_in[6];
  const int*   s2s_dst = (const int*)d_in[7];
  const float* Wp_stay = (const float*)d_in[8];
  const float* bp_stay = (const float*)d_in[9];
  const float* Wp_diag = (const float*)d_in[10];
  const float* bp_diag = (const float*)d_in[11];
  const float* Wl      = (const float*)d_in[12];
  const float* bl      = (const float*)d_in[13];
  const float* Wr      = (const float*)d_in[14];
  const float* ln_g    = (const float*)d_in[15];
  const float* ln_b    = (const float*)d_in[16];
  const float* Wc      = (const float*)d_in[17];
  const float* bc      = (const float*)d_in[18];

  // ---- workspace layout (float-slot units) ----
  float* ws = (float*)d_ws;
  unsigned short* hs_b   = (unsigned short*)(ws);             // 6.4M ush
  unsigned short* hd_b   = (unsigned short*)(ws + 3200000);   // 3.2M ush
  unsigned short* agg2_b = (unsigned short*)(ws + 4800000);   // 6.4M ush
  unsigned short* agg1_b = (unsigned short*)(ws + 8000000);   // 6.4M ush
  unsigned short* aggD_b = (unsigned short*)(ws + 11200000);  // 3.2M ush
  unsigned short* Wc6    = (unsigned short*)(ws + 12800000);  // 49152 ush
  unsigned short* Wps_b  = (unsigned short*)(ws + 12825000);  // 8192 ush
  unsigned short* Wpd_b  = (unsigned short*)(ws + 12830000);  // 4096 ush
  // partition arrays overlay agg region (dead until gather): 3*8*160000 u32 = 3.84M slots
  unsigned int* part = (unsigned int*)(ws + 4800000);
  int* ib = (int*)(ws + 12835000);
  int* cntD = ib;                   // 50000
  int* cnt1 = cntD + 50000;         // 100000
  int* cnt2 = cnt1 + 100000;        // 100000   (cnt region 250000, contiguous)
  int* bktD = cnt2 + 100000;        // 50000*64  = 3.2M
  int* bkt1 = bktD + 3200000;       // 100000*64 = 6.4M
  int* bkt2 = bkt1 + 6400000;       // 100000*64 = 6.4M
  int* gcur = bkt2 + 6400000;       // 24
  // end ≈ 116.4 MB

  const int cpcD = (NDIAG + 7) / 8;   // 6250
  const int cpcS = (NSTAY + 7) / 8;   // 12500

  // ---- weight prep + cnt/gcur zeroing ----
  k_prep<<<(61440 + 250000 + 24 + 255) / 256, 256, 0, stream>>>(
      Wp_stay, Wp_diag, Wl, Wr, Wps_b, Wpd_b, Wc6, cntD, gcur);

  // ---- bucket build: partition (coalesced) then XCD-local scatter ----
  k_part<<<3072, 256, 0, stream>>>(
      s2d_src, s2d_dst, cpcD,
      d2s_src, d2s_dst, cpcS,
      s2s_src, s2s_dst, cpcS,
      part, gcur);
  k_bscatter<<<2048, 256, 0, stream>>>(part, gcur,
      cntD, bktD, cpcD,
      cnt1, bkt1, cpcS,
      cnt2, bkt2, cpcS);

  // ---- input projections (MFMA, f32 nt in, bf16 out) ----
  k_projM<4><<<1563, 256, 0, stream>>>(x_stay, Wps_b, bp_stay, hs_b, NSTAY);
  k_projM<2><<<782, 256, 0, stream>>>(x_diag, Wpd_b, bp_diag, hd_b, NDIAG);

  const int GS = (NSTAY / 16 + 3) / 4;   // 1563
  const int GD = (NDIAG / 16 + 3) / 4;   // 782

  // ================= layer 0 =================
  {
    const unsigned short* W0 = Wc6;
    const unsigned short* W1 = Wc6 + 8192;
    const unsigned short* W2 = Wc6 + 16384;
    const float* bl0 = bl, *bl1 = bl + 64, *bl2 = bl + 128;
    const float* g = ln_g, *b = ln_b;

    k_gather3<<<4096, 256, 0, stream>>>(hs_b, hd_b,
        cnt2, bkt2, agg2_b, cnt1, bkt1, agg1_b, cntD, bktD, aggD_b,
        2 * NSTAY + NDIAG);
    k_sage2<0><<<GS, 256, 0, stream>>>(agg2_b, agg1_b, hs_b, W2, bl2, W1, bl1,
        g, b, NSTAY, nullptr, nullptr, nullptr);
    k_sageD<<<GD, 256, 0, stream>>>(aggD_b, hd_b, W0, bl0, g, b, NDIAG);
  }
  // ================= layer 1 (diag update dead: output depends only on h_stay) =================
  {
    const unsigned short* W1 = Wc6 + 8192 * 4;   // type 1, layer 1
    const unsigned short* W2 = Wc6 + 8192 * 5;   // type 2, layer 1
    const float* bl1 = bl + (3 + 1) * 64;
    const float* bl2 = bl + (3 + 2) * 64;
    const float* g = ln_g + 64, *b = ln_b + 64;

    k_gather3<<<4096, 256, 0, stream>>>(hs_b, hd_b,
        cnt2, bkt2, agg2_b, cnt1, bkt1, agg1_b, cntD, bktD, aggD_b,
        2 * NSTAY);   // skip dead s2d aggregation
    k_sage2<1><<<GS, 256, 0, stream>>>(agg2_b, agg1_b, hs_b, W2, bl2, W1, bl1,
        g, b, NSTAY, Wc, bc, (float*)d_out);
  }
}